// Round 1
// baseline (457.533 us; speedup 1.0000x reference)
//
#include <hip/hip_runtime.h>
#include <stdint.h>

// BiRealConv2d: y = conv2d(sign(x), scale[o]*sign(w)), NCHW, 3x3, pad 1.
// Exact integer XNOR-popcount formulation; see analysis in commit message.

#define HH 112
#define WW 112
#define CC 128
#define OO 128
#define NN 32
#define HP 114   // padded (halo = zeroed -> corrected via corr table)
#define WP 114

// ---------------- pass 1: pack sign(x) into 128-bit masks per pixel ----------------
__global__ __launch_bounds__(128) void pack_x_kernel(const float* __restrict__ x,
                                                     uint64_t* __restrict__ xb) {
  int w = threadIdx.x;
  int h = blockIdx.x;
  int n = blockIdx.y;
  if (w >= WW) return;
  const float* xp = x + (((size_t)n * CC) * HH + h) * WW + w;  // channel 0
  unsigned int m[4];
#pragma unroll
  for (int wd = 0; wd < 4; wd++) {
    unsigned int mm = 0u;
#pragma unroll
    for (int b = 0; b < 32; b++) {
      float v = xp[(size_t)(wd * 32 + b) * (HH * WW)];
      mm |= (v > 0.0f) ? (1u << b) : 0u;   // bit=1 -> +1, bit=0 -> -1
    }
    m[wd] = mm;
  }
  size_t oidx = (((size_t)n * HP + (h + 1)) * WP + (w + 1)) * 2;
  xb[oidx]     = (uint64_t)m[0] | ((uint64_t)m[1] << 32);
  xb[oidx + 1] = (uint64_t)m[2] | ((uint64_t)m[3] << 32);
}

// ---------------- pass 0: weight scale + bitmasks + border-correction table --------
__global__ __launch_bounds__(256) void prep_w_kernel(const float* __restrict__ wt,
                                                     uint64_t* __restrict__ wbits,
                                                     float* __restrict__ scale,
                                                     int* __restrict__ corr) {
  int o = blockIdx.x;
  const float* wo = wt + (size_t)o * (CC * 9);
  __shared__ unsigned int bits[9][4];
  __shared__ float red[256];
  int t = threadIdx.x;
  if (t < 36) ((unsigned int*)bits)[t] = 0u;
  __syncthreads();
  float s = 0.0f;
  for (int idx = t; idx < CC * 9; idx += 256) {
    float v = wo[idx];
    s += fabsf(v);
    int ci = idx / 9, tap = idx % 9;      // OIHW: [i][kh][kw], tap = kh*3+kw
    if (v > 0.0f) atomicOr(&bits[tap][ci >> 5], 1u << (ci & 31));
  }
  red[t] = s;
  __syncthreads();
  for (int st = 128; st > 0; st >>= 1) {
    if (t < st) red[t] += red[t + st];
    __syncthreads();
  }
  if (t == 0) {
    scale[o] = red[0] * (1.0f / 1152.0f);
    int c[9];
#pragma unroll
    for (int tap = 0; tap < 9; tap++) {
      uint64_t lo = (uint64_t)bits[tap][0] | ((uint64_t)bits[tap][1] << 32);
      uint64_t hi = (uint64_t)bits[tap][2] | ((uint64_t)bits[tap][3] << 32);
      wbits[o * 18 + tap * 2]     = lo;
      wbits[o * 18 + tap * 2 + 1] = hi;
      c[tap] = 128 - 2 * (__builtin_popcountll(lo) + __builtin_popcountll(hi));
    }
    // 9 border patterns: pat = ph*3+pw, ph/pw: 0=low edge,1=interior,2=high edge.
    for (int ph = 0; ph < 3; ph++)
      for (int pw = 0; pw < 3; pw++) {
        int sum = 0;
        for (int tap = 0; tap < 9; tap++) {
          int kh = tap / 3, kw = tap % 3;
          bool inv = (ph == 0 && kh == 0) || (ph == 2 && kh == 2) ||
                     (pw == 0 && kw == 0) || (pw == 2 && kw == 2);
          if (inv) sum += c[tap];  // spurious term from zeroed halo word
        }
        corr[o * 9 + ph * 3 + pw] = sum;
      }
  }
}

// ---------------- pass 2: XNOR-popcount conv -------------------------------------
__global__ __launch_bounds__(256) void conv_kernel(const uint64_t* __restrict__ xb,
                                                   const uint64_t* __restrict__ wbits,
                                                   const float* __restrict__ scale,
                                                   const int* __restrict__ corr,
                                                   float* __restrict__ out) {
  int t = threadIdx.x;
  // o-group is wave-uniform by construction; force SGPR so wbits/scale use s_load.
  int og = __builtin_amdgcn_readfirstlane(t >> 6);
  int wl = t & 63;
  int w = blockIdx.x * 64 + wl;
  int h = blockIdx.y;
  int n = blockIdx.z;
  if (w >= WW) return;
  int ph = (h == 0) ? 0 : ((h == HH - 1) ? 2 : 1);
  int pw = (w == 0) ? 0 : ((w == WW - 1) ? 2 : 1);
  int pat = ph * 3 + pw;

  // 9 taps x 128 bits, kept in VGPRs across the 32-deep o-loop.
  const uint64_t* xbase = xb + (((size_t)n * HP + h) * WP + w) * 2;  // padded (h-1+1, w-1+1)
  uint64_t xlo[9], xhi[9];
#pragma unroll
  for (int dh = 0; dh < 3; dh++)
#pragma unroll
    for (int dw = 0; dw < 3; dw++) {
      const ulonglong2 v = *(const ulonglong2*)(xbase + ((size_t)dh * WP + dw) * 2);
      xlo[dh * 3 + dw] = v.x;
      xhi[dh * 3 + dw] = v.y;
    }

  size_t obase = (((size_t)(n * OO + og * 32)) * HH + h) * WW + w;
  const int* corrp = corr + pat;
  for (int j = 0; j < 32; j++) {
    int o = og * 32 + j;                       // wave-uniform -> scalar loads below
    const uint64_t* wb = wbits + o * 18;
    int pc = 0;
#pragma unroll
    for (int tap = 0; tap < 9; tap++) {
      pc += __builtin_popcountll(xlo[tap] ^ wb[tap * 2]);
      pc += __builtin_popcountll(xhi[tap] ^ wb[tap * 2 + 1]);
    }
    int dot = 1152 - 2 * pc - corrp[o * 9];    // halo correction (0 for interior)
    out[obase] = scale[o] * (float)dot;
    obase += (size_t)HH * WW;
  }
}

extern "C" void kernel_launch(void* const* d_in, const int* in_sizes, int n_in,
                              void* d_out, int out_size, void* d_ws, size_t ws_size,
                              hipStream_t stream) {
  const float* x  = (const float*)d_in[0];
  const float* wt = (const float*)d_in[1];
  float* out = (float*)d_out;

  char* ws = (char*)d_ws;
  size_t xb_elems = (size_t)NN * HP * WP * 2;       // u64 count = 831,744 (6.65 MB)
  uint64_t* xb    = (uint64_t*)ws;
  size_t off = xb_elems * 8;
  uint64_t* wbits = (uint64_t*)(ws + off); off += (size_t)OO * 18 * 8;  // 18 KB
  float* scale    = (float*)(ws + off);    off += (size_t)OO * 4;
  int* corr       = (int*)(ws + off);      off += (size_t)OO * 9 * 4;

  // zero halo (and interior, overwritten by pack) — ws is re-poisoned every call
  hipMemsetAsync(xb, 0, xb_elems * 8, stream);
  hipLaunchKernelGGL(pack_x_kernel, dim3(HH, NN), dim3(128), 0, stream, x, xb);
  hipLaunchKernelGGL(prep_w_kernel, dim3(OO), dim3(256), 0, stream, wt, wbits, scale, corr);
  hipLaunchKernelGGL(conv_kernel, dim3(2, HH, NN), dim3(256), 0, stream,
                     xb, wbits, scale, corr, out);
}